// Round 1
// baseline (382.232 us; speedup 1.0000x reference)
//
#include <hip/hip_runtime.h>
#include <math.h>

#define B_ 4
#define K_ 4096
#define C_ 256
#define H_ 128
#define RAD 5
#define ROWS 8

typedef float floatx4 __attribute__((ext_vector_type(4)));

#define NSCORE (B_ * K_ / 16)      // 1024 score blocks (16 tokens each)
#define NCOLSUM (B_ * K_ / 32)     // 512 colsum blocks (32 rows each)

// ws layout (floats): s: [B_*K_] @0, Ssum: [B_*C_] @ B_*K_   (~68 KB)
// colsum partials live in d_out's weights region (overwritten later by attn).

// ---------------- Kernel A (fused): score + colsum_partial ----------------
// Blocks [0, NSCORE): 16 tokens per 256-thread block, two independent
//   128-thread halves; thread (tid&127) owns hidden unit for 8 tokens.
//   Fusing 16 tokens/block halves W1 L2 re-read traffic vs 8 tokens/block.
// Blocks [NSCORE, NSCORE+NCOLSUM): per-batch column-sum partials (BW-bound),
//   runs concurrently with the VALU-bound score path instead of serialized.
__global__ __launch_bounds__(256) void fused_a(
    const float* __restrict__ x, const float* __restrict__ W1,
    const float* __restrict__ b1, const float* __restrict__ W2,
    const float* __restrict__ b2, float* __restrict__ s_out,
    float* __restrict__ partial)
{
    const int tid = threadIdx.x;

    if (blockIdx.x >= NSCORE) {
        // ---- colsum_partial: 32 rows per block, thread owns channel tid ----
        const int blk = blockIdx.x - NSCORE;
        const float* base = x + (size_t)blk * 32 * C_ + tid;
        float a0 = 0.f, a1 = 0.f, a2 = 0.f, a3 = 0.f;
        #pragma unroll
        for (int kk = 0; kk < 32; kk += 4) {
            a0 += base[(size_t)(kk + 0) * C_];
            a1 += base[(size_t)(kk + 1) * C_];
            a2 += base[(size_t)(kk + 2) * C_];
            a3 += base[(size_t)(kk + 3) * C_];
        }
        partial[(size_t)blk * C_ + tid] = (a0 + a1) + (a2 + a3);
        return;
    }

    // ---- score: 16 tokens/block; half = tid>>7 owns tokens [half*8, half*8+8) ----
    const int htid = tid & 127;
    const int half = tid >> 7;
    const int t0 = blockIdx.x * 16 + half * 8;

    const float* xr[8];
    #pragma unroll
    for (int t = 0; t < 8; ++t) xr[t] = x + (size_t)(t0 + t) * C_;

    float acc[8];
    float binit = b1[htid];
    #pragma unroll
    for (int t = 0; t < 8; ++t) acc[t] = binit;

    for (int c = 0; c < C_; c += 4) {
        float w0 = W1[(c + 0) * H_ + htid];
        float w1 = W1[(c + 1) * H_ + htid];
        float w2 = W1[(c + 2) * H_ + htid];
        float w3 = W1[(c + 3) * H_ + htid];
        #pragma unroll
        for (int t = 0; t < 8; ++t) {
            floatx4 xv = *(const floatx4*)&xr[t][c];
            acc[t] = fmaf(xv.x, w0, acc[t]);
            acc[t] = fmaf(xv.y, w1, acc[t]);
            acc[t] = fmaf(xv.z, w2, acc[t]);
            acc[t] = fmaf(xv.w, w3, acc[t]);
        }
    }

    // waves 0,1 belong to half 0; waves 2,3 to half 1.
    __shared__ float red[4][8];
    float w2v = W2[htid];
    #pragma unroll
    for (int t = 0; t < 8; ++t) {
        float p = tanhf(acc[t]) * w2v;
        #pragma unroll
        for (int off = 32; off > 0; off >>= 1) p += __shfl_down(p, off);
        if ((tid & 63) == 0) red[tid >> 6][t] = p;
    }
    __syncthreads();
    if (tid < 16) {
        const int h = tid >> 3;
        const int t = tid & 7;
        s_out[blockIdx.x * 16 + h * 8 + t] = red[2 * h][t] + red[2 * h + 1][t] + b2[0];
    }
}

// ---------------- Kernel B: final column-sum reduction ----------------
__global__ __launch_bounds__(256) void colsum_final(
    const float* __restrict__ partial, float* __restrict__ Ssum)
{
    const int tid = threadIdx.x;
    const int b = blockIdx.x;
    float acc = 0.f;
    for (int chunk = 0; chunk < 128; ++chunk)
        acc += partial[(size_t)(b * 128 + chunk) * C_ + tid];
    Ssum[b * C_ + tid] = acc;
}

// ---------------- Kernel C: 8 query rows per block ----------------
// Stage s-band + x-band in LDS once; softmax scalars for the 8 rows computed
// in parallel by threads 0..7; then stream 8 weights rows (139 KB/block) and
// 8 weighted rows. Plain stores (A/B vs nt: fills hit 6.4 TB/s with plain).
__global__ __launch_bounds__(256) void attn_kernel(
    const float* __restrict__ x, const float* __restrict__ s,
    const float* __restrict__ Ssum, float* __restrict__ out)
{
    const int tid = threadIdx.x;
    const int blk = blockIdx.x;                   // b*(K_/ROWS) + tile
    const int b  = blk >> 9;                      // K_/ROWS = 512
    const int i0 = (blk & 511) * ROWS;

    const int j0t = max(0, i0 - RAD);
    const int j1t = min(K_ - 1, i0 + ROWS - 1 + RAD);
    const int ntok = j1t - j0t + 1;               // <= 18

    __shared__ float xs[ROWS + 2 * RAD][C_];      // 18 KB
    __shared__ float sb[ROWS + 2 * RAD];
    __shared__ float wb[ROWS][2 * RAD + 1];
    __shared__ float woff[ROWS];

    if (tid < ntok) sb[tid] = s[b * K_ + j0t + tid];
    const floatx4* xsrc = (const floatx4*)(x + ((size_t)b * K_ + j0t) * C_);
    floatx4* xdst = (floatx4*)&xs[0][0];
    for (int f = tid; f < ntok * (C_ / 4); f += 256) xdst[f] = xsrc[f];
    __syncthreads();

    if (tid < ROWS) {
        const int i = i0 + tid;
        const int j0 = max(0, i - RAD), j1 = min(K_ - 1, i + RAD);
        const int nb = j1 - j0 + 1;
        float m = 0.f;                            // off-band score 0 => max >= 0
        for (int j = j0; j <= j1; ++j) m = fmaxf(m, sb[j - j0t]);
        float e0 = expf(-m);
        float D = (float)(K_ - nb) * e0;
        for (int j = j0; j <= j1; ++j) {
            float e = expf(sb[j - j0t] - m);
            wb[tid][j - j0] = e;
            D += e;
        }
        float inv = 1.0f / D;
        for (int jj = 0; jj < nb; ++jj) wb[tid][jj] *= inv;
        woff[tid] = e0 * inv;
    }
    __syncthreads();

    const float sc = Ssum[b * C_ + tid];

    // ---- weights rows: 8 x 4096 floats; per row, thread writes f4 idx tid+256q ----
    #pragma unroll
    for (int r = 0; r < ROWS; ++r) {
        const int i = i0 + r;
        const int j0 = max(0, i - RAD), j1 = min(K_ - 1, i + RAD);
        const float wo = woff[r];
        floatx4* wrow4 = (floatx4*)(out + (size_t)B_ * K_ * C_ + ((size_t)b * K_ + i) * K_);
        #pragma unroll
        for (int q = 0; q < 4; ++q) {
            const int f = tid + 256 * q;
            const int jb = f * 4;
            floatx4 v = { wo, wo, wo, wo };
            if (jb + 3 >= j0 && jb <= j1) {       // touches band (<=2 threads/row/q)
                if (jb + 0 >= j0 && jb + 0 <= j1) v.x = wb[r][jb + 0 - j0];
                if (jb + 1 >= j0 && jb + 1 <= j1) v.y = wb[r][jb + 1 - j0];
                if (jb + 2 >= j0 && jb + 2 <= j1) v.z = wb[r][jb + 2 - j0];
                if (jb + 3 >= j0 && jb + 3 <= j1) v.w = wb[r][jb + 3 - j0];
            }
            wrow4[f] = v;
        }
    }

    // ---- weighted rows: 8 x 256 floats; thread owns channel tid ----
    #pragma unroll
    for (int r = 0; r < ROWS; ++r) {
        const int i = i0 + r;
        const int j0 = max(0, i - RAD), j1 = min(K_ - 1, i + RAD);
        const float wo = woff[r];
        float acc = wo * sc;
        for (int j = j0; j <= j1; ++j)
            acc = fmaf(wb[r][j - j0] - wo, xs[j - j0t][tid], acc);
        out[((size_t)b * K_ + i) * C_ + tid] = acc;
    }
}

extern "C" void kernel_launch(void* const* d_in, const int* in_sizes, int n_in,
                              void* d_out, int out_size, void* d_ws, size_t ws_size,
                              hipStream_t stream) {
    const float* x  = (const float*)d_in[0];
    const float* W1 = (const float*)d_in[1];
    const float* b1 = (const float*)d_in[2];
    const float* W2 = (const float*)d_in[3];
    const float* b2 = (const float*)d_in[4];
    float* out = (float*)d_out;

    float* ws   = (float*)d_ws;
    float* s    = ws;                             // B_*K_
    float* Ssum = ws + B_ * K_;                   // B_*C_
    float* partial = out + (size_t)B_ * K_ * C_;  // scratch in weights region

    fused_a     <<<NSCORE + NCOLSUM, 256, 0, stream>>>(x, W1, b1, W2, b2, s, partial);
    colsum_final<<<B_,               256, 0, stream>>>(partial, Ssum);
    attn_kernel <<<B_ * K_ / ROWS,   256, 0, stream>>>(x, s, Ssum, out);
}

// Round 2
// 378.946 us; speedup vs baseline: 1.0087x; 1.0087x over previous
//
#include <hip/hip_runtime.h>
#include <math.h>

#define B_ 4
#define K_ 4096
#define C_ 256
#define H_ 128
#define RAD 5
#define ROWS 8

typedef float floatx4 __attribute__((ext_vector_type(4)));

#define NSCORE (B_ * K_ / 16)      // 1024 score blocks (16 tokens each)
#define NCOLSUM (B_ * K_ / 32)     // 512 colsum blocks (32 rows each)

// ws layout (floats): s: [B_*K_] @0, Ssum: [B_*C_] @ B_*K_   (~68 KB)
// Ssum is zeroed by a 4KB memset node, then accumulated via atomics in fused_a.

// ---------------- Kernel A (fused): score + colsum ----------------
// Blocks [0, NSCORE): 16 tokens per 256-thread block, two independent
//   128-thread halves; thread (tid&127) owns hidden unit for 8 tokens.
// Blocks [NSCORE, NSCORE+NCOLSUM): per-batch column sums, reduced 32 rows
//   per block then atomicAdd'd straight into Ssum (128 atomics/address,
//   ~1-2 us tail, hidden under the score path). Removes the colsum_final
//   kernel + its launch gap + the partial-buffer round trip.
__global__ __launch_bounds__(256) void fused_a(
    const float* __restrict__ x, const float* __restrict__ W1,
    const float* __restrict__ b1, const float* __restrict__ W2,
    const float* __restrict__ b2, float* __restrict__ s_out,
    float* __restrict__ Ssum)
{
    const int tid = threadIdx.x;

    if (blockIdx.x >= NSCORE) {
        // ---- colsum: 32 rows per block, thread owns channel tid ----
        const int blk = blockIdx.x - NSCORE;
        const int b = blk >> 7;                   // K_/32 = 128 blocks per batch
        const float* base = x + (size_t)blk * 32 * C_ + tid;
        float a0 = 0.f, a1 = 0.f, a2 = 0.f, a3 = 0.f;
        #pragma unroll
        for (int kk = 0; kk < 32; kk += 4) {
            a0 += base[(size_t)(kk + 0) * C_];
            a1 += base[(size_t)(kk + 1) * C_];
            a2 += base[(size_t)(kk + 2) * C_];
            a3 += base[(size_t)(kk + 3) * C_];
        }
        atomicAdd(&Ssum[b * C_ + tid], (a0 + a1) + (a2 + a3));
        return;
    }

    // ---- score: 16 tokens/block; half = tid>>7 owns tokens [half*8, half*8+8) ----
    const int htid = tid & 127;
    const int half = tid >> 7;
    const int t0 = blockIdx.x * 16 + half * 8;

    const float* xr[8];
    #pragma unroll
    for (int t = 0; t < 8; ++t) xr[t] = x + (size_t)(t0 + t) * C_;

    float acc[8];
    float binit = b1[htid];
    #pragma unroll
    for (int t = 0; t < 8; ++t) acc[t] = binit;

    for (int c = 0; c < C_; c += 4) {
        float w0 = W1[(c + 0) * H_ + htid];
        float w1 = W1[(c + 1) * H_ + htid];
        float w2 = W1[(c + 2) * H_ + htid];
        float w3 = W1[(c + 3) * H_ + htid];
        #pragma unroll
        for (int t = 0; t < 8; ++t) {
            floatx4 xv = *(const floatx4*)&xr[t][c];
            acc[t] = fmaf(xv.x, w0, acc[t]);
            acc[t] = fmaf(xv.y, w1, acc[t]);
            acc[t] = fmaf(xv.z, w2, acc[t]);
            acc[t] = fmaf(xv.w, w3, acc[t]);
        }
    }

    // waves 0,1 belong to half 0; waves 2,3 to half 1.
    __shared__ float red[4][8];
    float w2v = W2[htid];
    #pragma unroll
    for (int t = 0; t < 8; ++t) {
        float p = tanhf(acc[t]) * w2v;
        #pragma unroll
        for (int off = 32; off > 0; off >>= 1) p += __shfl_down(p, off);
        if ((tid & 63) == 0) red[tid >> 6][t] = p;
    }
    __syncthreads();
    if (tid < 16) {
        const int h = tid >> 3;
        const int t = tid & 7;
        s_out[blockIdx.x * 16 + h * 8 + t] = red[2 * h][t] + red[2 * h + 1][t] + b2[0];
    }
}

// ---------------- Kernel C: 8 query rows per block ----------------
// Stage s-band + x-band in LDS once; softmax scalars for the 8 rows computed
// in parallel by threads 0..7; then stream 8 weights rows (139 KB/block) and
// 8 weighted rows. Plain stores (A/B vs nt: fills hit 6.4 TB/s with plain).
__global__ __launch_bounds__(256) void attn_kernel(
    const float* __restrict__ x, const float* __restrict__ s,
    const float* __restrict__ Ssum, float* __restrict__ out)
{
    const int tid = threadIdx.x;
    const int blk = blockIdx.x;                   // b*(K_/ROWS) + tile
    const int b  = blk >> 9;                      // K_/ROWS = 512
    const int i0 = (blk & 511) * ROWS;

    const int j0t = max(0, i0 - RAD);
    const int j1t = min(K_ - 1, i0 + ROWS - 1 + RAD);
    const int ntok = j1t - j0t + 1;               // <= 18

    __shared__ float xs[ROWS + 2 * RAD][C_];      // 18 KB
    __shared__ float sb[ROWS + 2 * RAD];
    __shared__ float wb[ROWS][2 * RAD + 1];
    __shared__ float woff[ROWS];

    if (tid < ntok) sb[tid] = s[b * K_ + j0t + tid];
    const floatx4* xsrc = (const floatx4*)(x + ((size_t)b * K_ + j0t) * C_);
    floatx4* xdst = (floatx4*)&xs[0][0];
    for (int f = tid; f < ntok * (C_ / 4); f += 256) xdst[f] = xsrc[f];
    __syncthreads();

    if (tid < ROWS) {
        const int i = i0 + tid;
        const int j0 = max(0, i - RAD), j1 = min(K_ - 1, i + RAD);
        const int nb = j1 - j0 + 1;
        float m = 0.f;                            // off-band score 0 => max >= 0
        for (int j = j0; j <= j1; ++j) m = fmaxf(m, sb[j - j0t]);
        float e0 = expf(-m);
        float D = (float)(K_ - nb) * e0;
        for (int j = j0; j <= j1; ++j) {
            float e = expf(sb[j - j0t] - m);
            wb[tid][j - j0] = e;
            D += e;
        }
        float inv = 1.0f / D;
        for (int jj = 0; jj < nb; ++jj) wb[tid][jj] *= inv;
        woff[tid] = e0 * inv;
    }
    __syncthreads();

    const float sc = Ssum[b * C_ + tid];

    // ---- weights rows: 8 x 4096 floats; per row, thread writes f4 idx tid+256q ----
    #pragma unroll
    for (int r = 0; r < ROWS; ++r) {
        const int i = i0 + r;
        const int j0 = max(0, i - RAD), j1 = min(K_ - 1, i + RAD);
        const float wo = woff[r];
        floatx4* wrow4 = (floatx4*)(out + (size_t)B_ * K_ * C_ + ((size_t)b * K_ + i) * K_);
        #pragma unroll
        for (int q = 0; q < 4; ++q) {
            const int f = tid + 256 * q;
            const int jb = f * 4;
            floatx4 v = { wo, wo, wo, wo };
            if (jb + 3 >= j0 && jb <= j1) {       // touches band (<=2 threads/row/q)
                if (jb + 0 >= j0 && jb + 0 <= j1) v.x = wb[r][jb + 0 - j0];
                if (jb + 1 >= j0 && jb + 1 <= j1) v.y = wb[r][jb + 1 - j0];
                if (jb + 2 >= j0 && jb + 2 <= j1) v.z = wb[r][jb + 2 - j0];
                if (jb + 3 >= j0 && jb + 3 <= j1) v.w = wb[r][jb + 3 - j0];
            }
            wrow4[f] = v;
        }
    }

    // ---- weighted rows: 8 x 256 floats; thread owns channel tid ----
    #pragma unroll
    for (int r = 0; r < ROWS; ++r) {
        const int i = i0 + r;
        const int j0 = max(0, i - RAD), j1 = min(K_ - 1, i + RAD);
        const float wo = woff[r];
        float acc = wo * sc;
        for (int j = j0; j <= j1; ++j)
            acc = fmaf(wb[r][j - j0] - wo, xs[j - j0t][tid], acc);
        out[((size_t)b * K_ + i) * C_ + tid] = acc;
    }
}

extern "C" void kernel_launch(void* const* d_in, const int* in_sizes, int n_in,
                              void* d_out, int out_size, void* d_ws, size_t ws_size,
                              hipStream_t stream) {
    const float* x  = (const float*)d_in[0];
    const float* W1 = (const float*)d_in[1];
    const float* b1 = (const float*)d_in[2];
    const float* W2 = (const float*)d_in[3];
    const float* b2 = (const float*)d_in[4];
    float* out = (float*)d_out;

    float* ws   = (float*)d_ws;
    float* s    = ws;                             // B_*K_
    float* Ssum = ws + B_ * K_;                   // B_*C_

    hipMemsetAsync(Ssum, 0, B_ * C_ * sizeof(float), stream);
    fused_a    <<<NSCORE + NCOLSUM, 256, 0, stream>>>(x, W1, b1, W2, b2, s, Ssum);
    attn_kernel<<<B_ * K_ / ROWS,   256, 0, stream>>>(x, s, Ssum, out);
}